// Round 12
// baseline (261.398 us; speedup 1.0000x reference)
//
#include <hip/hip_runtime.h>

typedef unsigned short ushort;
typedef unsigned int uint;

constexpr int B = 2, C = 64, H = 112, W = 112;
constexpr int HW = H * W;          // 12544
constexpr int NBLK = 392;          // 8 patches x 49 tiles
constexpr float EPS_LN = 1e-6f, EPS_NORM = 1e-7f;

__device__ __forceinline__ float rcp_fast(float x) { return __builtin_amdgcn_rcpf(x); }
__device__ __forceinline__ float sigmoid_f(float x) { return rcp_fast(1.f + __expf(-x)); }
// Force wave-uniformity so the compiler emits s_load for weight rows.
__device__ __forceinline__ int uni(int x) { return __builtin_amdgcn_readfirstlane(x); }

// f32 -> bf16 bits (round-nearest-even) + pair pack/unpack.
__device__ __forceinline__ ushort rne16(float x) {
    uint u = __float_as_uint(x);
    u += 0x7fffu + ((u >> 16) & 1u);
    return (ushort)(u >> 16);
}
__device__ __forceinline__ uint pack2(float a, float b) {
    return (uint)rne16(a) | ((uint)rne16(b) << 16);
}
__device__ __forceinline__ float2 up2(uint u) {
    return make_float2(__uint_as_float(u << 16), __uint_as_float(u & 0xffff0000u));
}

// XCD-patch swizzle: blk&7 -> (image, quadrant) on one XCD; blk>>3 -> tile in
// the 7x7-tile patch. Patch working set fits the 4 MB per-XCD L2.
__device__ __forceinline__ void decode_blk(int blk, int& b, int& ty, int& tx) {
    int p8 = blk & 7, i = blk >> 3;
    b = p8 >> 2;
    int quad = p8 & 3;
    int lty = i / 7, ltx = i - lty * 7;
    ty = (quad >> 1) * 7 + lty;
    tx = (quad & 1) * 7 + ltx;
}

// ---------------------------------------------------------------------------
// Single kernel: A' computes range_proj(px) for all 196 halo pixels in-block
// (3.06x redundant, k1-style lane=pixel o-split structure), then bilateral
// weights + gated fixup + normalize + neighborhood reduction + output_proj.
// 256 threads / 8x8 tile. Halos bf16 in LDS; compute f32; weights via s_load.
// bf16 halo row r = 128 B = 8 chunks of 16 B; chunk q stored at q^(r&7).
// ---------------------------------------------------------------------------
__global__ __launch_bounds__(256, 2) void kfused(
    const float* __restrict__ sem,  const float* __restrict__ spat,
    const float* __restrict__ rw1, const float* __restrict__ rb1,
    const float* __restrict__ rg,  const float* __restrict__ rbe,
    const float* __restrict__ rw2, const float* __restrict__ rb2,
    const float* __restrict__ fw1, const float* __restrict__ fb1,
    const float* __restrict__ fg,  const float* __restrict__ fbe,
    const float* __restrict__ fw2, const float* __restrict__ fb2,
    const float* __restrict__ w1, const float* __restrict__ b1,
    const float* __restrict__ g,  const float* __restrict__ be,
    const float* __restrict__ w2, const float* __restrict__ b2,
    const float* __restrict__ sigma_, float* __restrict__ out)
{
    __shared__ __align__(16) float smem[13508];          // 54032 B arena
    ushort* halo16 = (ushort*)smem;                      // 196x64 bf16 px/spat halo
    float*  comb   = smem + 6272;                        // 49x64
    float*  fscr   = smem + 9408;                        // 49x64 (dedicated in P3)
    float*  sqn_l  = smem + 12544;                       // 196
    float*  pm     = smem + 12740;
    float*  ps     = smem + 12996;
    float*  pt     = smem + 13252;                       // ends at 13508
    float*  f_scrA = smem + 6272;                        // 64x64 over dead comb/fscr

    const int tid = threadIdx.x, lane = tid & 63, wv = tid >> 6;
    int b, ty, tx; decode_blk(blockIdx.x, b, ty, tx);
    const int h = ty * 8 + (lane >> 3), w = tx * 8 + (lane & 7);
    const int hw = h * W + w;
    const int h0 = ty * 8 - 3, w0 = tx * 8 - 3;
    const int o0 = uni(wv * 16);

    // ============ A': range_proj over the 196-px halo, 4 groups of 64 ============
    for (int gph = 0; gph < 4; ++gph) {
        const int r = gph * 64 + lane;
        const int rr = (r < 196) ? r : 195;              // clamp (safe addresses)
        const int ry = (rr * 2341) >> 15, rx = rr - ry * 14;   // exact /14, rr<256
        const int hh = h0 + ry, ww = w0 + rx;
        const bool valid = (r < 196) &&
            (unsigned)hh < (unsigned)H && (unsigned)ww < (unsigned)W;
        const int soff = hh * W + ww;

        float sv[64];
#pragma unroll
        for (int k = 0; k < 64; ++k)
            sv[k] = valid ? sem[(size_t)(b * 64 + k) * HW + soff] : 0.f;

        float macc = 0.f, sacc = 0.f;
        for (int j = 0; j < 16; ++j) {
            const int o = o0 + j;                 // uniform -> s_load weight row
            const float* wr = &rw1[o * 64];
            float a0 = 0, a1 = 0, a2 = 0, a3 = 0;
#pragma unroll
            for (int k = 0; k < 64; k += 4) {
                a0 += wr[k] * sv[k];       a1 += wr[k + 1] * sv[k + 1];
                a2 += wr[k + 2] * sv[k + 2]; a3 += wr[k + 3] * sv[k + 3];
            }
            float f = (a0 + a1) + (a2 + a3) + rb1[o];
            f_scrA[o * 64 + lane] = f;     // bank=lane%32: 2-way, free
            macc += f; sacc += f * f;
        }
        pm[wv * 64 + lane] = macc; ps[wv * 64 + lane] = sacc;
        __syncthreads();                                  // B1
        float m  = (pm[lane] + pm[64 + lane] + pm[128 + lane] + pm[192 + lane]) * (1.f / 64.f);
        float va = (ps[lane] + ps[64 + lane] + ps[128 + lane] + ps[192 + lane]) * (1.f / 64.f) - m * m;
        float rstd = rsqrtf(va + EPS_LN);

        float s[64];
#pragma unroll
        for (int k = 0; k < 64; ++k) {
            float y = rg[k] * (f_scrA[k * 64 + lane] - m) * rstd + rbe[k];
            s[k] = y * sigmoid_f(y);
        }
        float z[16];
        float sq = 0.f;
        for (int j = 0; j < 16; ++j) {
            const int o = o0 + j;                 // uniform
            const float* wr = &rw2[o * 64];
            float a0 = 0, a1 = 0, a2 = 0, a3 = 0;
#pragma unroll
            for (int k = 0; k < 64; k += 4) {
                a0 += wr[k] * s[k];        a1 += wr[k + 1] * s[k + 1];
                a2 += wr[k + 2] * s[k + 2]; a3 += wr[k + 3] * s[k + 3];
            }
            float zz = (a0 + a1) + (a2 + a3) + rb2[o];
            z[j] = valid ? zz : 0.f;              // reference zero-pads px
            sq += z[j] * z[j];
        }
        if (r < 196) {
            const int rsw = r & 7;
            ushort* rowp = &halo16[r << 6];
#pragma unroll
            for (int jp = 0; jp < 8; ++jp) {
                int c = o0 + 2 * jp;
                int q = (c >> 3) ^ rsw;           // chunk swizzle
                *(uint*)&rowp[(q << 3) + (c & 7)] = pack2(z[2 * jp], z[2 * jp + 1]);
            }
        }
        pt[wv * 64 + lane] = sq;
        __syncthreads();                                  // B2 (s-reads done too)
        if (wv == 0 && r < 196)
            sqn_l[r] = pt[lane] + pt[64 + lane] + pt[128 + lane] + pt[192 + lane];
        // next group's pt/f_scrA writes sit behind its B1 -> safe
    }
    __syncthreads();   // A' halo16/sqn_l complete for P2

    // ---- P2: bilateral weights, neighbors split across waves ----
    const int rbase = (lane >> 3) * 14 + (lane & 7);
    const int rp = rbase + 45;
    float cv[64];
#pragma unroll
    for (int q = 0; q < 8; ++q) {
        uint4 v = *(const uint4*)&halo16[(rp << 6) + ((q ^ (rp & 7)) << 3)];
        float2 p0_ = up2(v.x), p1_ = up2(v.y), p2_ = up2(v.z), p3_ = up2(v.w);
        cv[8 * q + 0] = p0_.x; cv[8 * q + 1] = p0_.y;
        cv[8 * q + 2] = p1_.x; cv[8 * q + 3] = p1_.y;
        cv[8 * q + 4] = p2_.x; cv[8 * q + 5] = p2_.y;
        cv[8 * q + 6] = p3_.x; cv[8 * q + 7] = p3_.y;
    }
    const float sqc = sqn_l[rp];
    const float sg_ = sigma_[0];
    const float inv2s2 = rcp_fast(2.f * sg_ * sg_);
    for (int i = 0; i < 13; ++i) {
        int n = uni(wv + 4 * i);
        if (n < 49) {
            int ryn = n / 7, rxn = n - ryn * 7;
            int dy = ryn - 3, dx = rxn - 3;
            int rn = rbase + ryn * 14 + rxn;
            float d0 = 0, d1 = 0, d2 = 0, d3 = 0;
#pragma unroll
            for (int q = 0; q < 8; ++q) {
                uint4 v = *(const uint4*)&halo16[(rn << 6) + ((q ^ (rn & 7)) << 3)];
                float2 a = up2(v.x), bb = up2(v.y), c = up2(v.z), d = up2(v.w);
                d0 += a.x  * cv[8 * q + 0]; d1 += a.y  * cv[8 * q + 1];
                d2 += bb.x * cv[8 * q + 2]; d3 += bb.y * cv[8 * q + 3];
                d0 += c.x  * cv[8 * q + 4]; d1 += c.y  * cv[8 * q + 5];
                d2 += d.x  * cv[8 * q + 6]; d3 += d.y  * cv[8 * q + 7];
            }
            float dot = (d0 + d1) + (d2 + d3);
            float dist2 = fmaxf(sqn_l[rn] + sqc - 2.f * dot, 0.f);
            bool validn = (unsigned)(h + dy) < (unsigned)H && (unsigned)(w + dx) < (unsigned)W;
            float d2n = (float)(dy * dy + dx * dx);
            comb[n * 64 + lane] = validn ? __expf(-(dist2 * (1.f / 128.f) + d2n * inv2s2)) : 0.f;
        }
    }
    __syncthreads();   // all px-halo reads + comb writes done

    // ---- svv load (P3 input): latency hides under P4 stores / P3 s_loads ----
    float svv[64];
#pragma unroll
    for (int k = 0; k < 64; ++k) svv[k] = sem[(size_t)(b * 64 + k) * HW + hw];

    // ---- P4 (issued first, overlaps P3): restage halo with spat (bf16) ----
    {
        const int ry16 = tid >> 4, rx16 = tid & 15;
        if ((ry16 < 14) & (rx16 < 14)) {
            const int r = ry16 * 14 + rx16;
            const int hh = h0 + ry16, ww = w0 + rx16;
            const bool valid = (unsigned)hh < (unsigned)H && (unsigned)ww < (unsigned)W;
            const int soff = hh * W + ww;
            const int rsw = (r & 7), rb_ = r << 6;
#pragma unroll
            for (int cq = 0; cq < 8; ++cq) {
                uint4 v = make_uint4(0u, 0u, 0u, 0u);
                if (valid) {
                    const float* sp = &spat[(size_t)(b * 64 + 8 * cq) * HW + soff];
                    v.x = pack2(sp[0],      sp[HW]);
                    v.y = pack2(sp[2 * HW], sp[3 * HW]);
                    v.z = pack2(sp[4 * HW], sp[5 * HW]);
                    v.w = pack2(sp[6 * HW], sp[7 * HW]);
                }
                *(uint4*)&halo16[rb_ + ((cq ^ rsw) << 3)] = v;
            }
        }
    }

    // ---- P3: gated fixup (fscr dedicated; runs while P4 loads drain) ----
    float cb[49];
#pragma unroll
    for (int n = 0; n < 49; ++n) cb[n] = comb[n * 64 + lane];
    float macc = 0.f, sacc = 0.f;
    for (int i = 0; i < 13; ++i) {
        const int o = uni(wv + 4 * i);   // uniform -> s_load weight row
        if (o < 49) {
            const float* wr = &fw1[o * 113];
            float a0 = 0, a1 = 0, a2 = 0, a3 = 0;
#pragma unroll
            for (int k = 0; k < 48; k += 4) {
                a0 += wr[k] * cb[k];       a1 += wr[k + 1] * cb[k + 1];
                a2 += wr[k + 2] * cb[k + 2]; a3 += wr[k + 3] * cb[k + 3];
            }
            a0 += wr[48] * cb[48];
            const float* wr2 = wr + 49;
#pragma unroll
            for (int k = 0; k < 64; k += 4) {
                a0 += wr2[k] * svv[k];       a1 += wr2[k + 1] * svv[k + 1];
                a2 += wr2[k + 2] * svv[k + 2]; a3 += wr2[k + 3] * svv[k + 3];
            }
            float f = (a0 + a1) + (a2 + a3) + fb1[o];
            fscr[o * 64 + lane] = f;
            macc += f; sacc += f * f;
        }
    }
    pm[wv * 64 + lane] = macc; ps[wv * 64 + lane] = sacc;
    __syncthreads();
    {
        float m  = (pm[lane] + pm[64 + lane] + pm[128 + lane] + pm[192 + lane]) * (1.f / 49.f);
        float va = (ps[lane] + ps[64 + lane] + ps[128 + lane] + ps[192 + lane]) * (1.f / 49.f) - m * m;
        float rstd = rsqrtf(va + EPS_LN);
        float s[49];
#pragma unroll
        for (int k = 0; k < 49; ++k) {
            float y = fg[k] * (fscr[k * 64 + lane] - m) * rstd + fbe[k];
            s[k] = y * sigmoid_f(y);
        }
        float tacc = 0.f;
        for (int i = 0; i < 13; ++i) {
            const int o = uni(wv + 4 * i);
            if (o < 49) {
                const float* wr = &fw2[o * 49];
                float a0 = 0, a1 = 0, a2 = 0, a3 = 0;
#pragma unroll
                for (int k = 0; k < 48; k += 4) {
                    a0 += wr[k] * s[k];       a1 += wr[k + 1] * s[k + 1];
                    a2 += wr[k + 2] * s[k + 2]; a3 += wr[k + 3] * s[k + 3];
                }
                a0 += wr[48] * s[48];
                float fo = (a0 + a1) + (a2 + a3) + fb2[o];
                float gate = 1.f + sigmoid_f(fo);
                float cx = comb[o * 64 + lane] * gate;   // own rows: no race
                comb[o * 64 + lane] = cx;
                tacc += cx;
            }
        }
        pt[wv * 64 + lane] = tacc;
    }
    __syncthreads();   // P3 done AND P4 staging visible
    const float inv = rcp_fast(pt[lane] + pt[64 + lane] + pt[128 + lane] + pt[192 + lane] + EPS_NORM);

    // ---- P5: weighted neighborhood reduction (bf16 spat halo) ----
    const int c0 = uni(wv * 16);
    const int qq0 = c0 >> 3;            // wave's two 8-ch chunks
    float acc[16];
#pragma unroll
    for (int j = 0; j < 16; ++j) acc[j] = 0.f;
    for (int n = 0; n < 49; ++n) {
        int ryn = n / 7, rxn = n - ryn * 7;
        int rn = rbase + ryn * 14 + rxn;
        float cn = comb[n * 64 + lane] * inv;
        const int rb_ = rn << 6, rsw = rn & 7;
#pragma unroll
        for (int q = 0; q < 2; ++q) {
            uint4 v = *(const uint4*)&halo16[rb_ + (((qq0 + q) ^ rsw) << 3)];
            float2 a = up2(v.x), bb = up2(v.y), c = up2(v.z), d = up2(v.w);
            acc[8 * q + 0] += cn * a.x;  acc[8 * q + 1] += cn * a.y;
            acc[8 * q + 2] += cn * bb.x; acc[8 * q + 3] += cn * bb.y;
            acc[8 * q + 4] += cn * c.x;  acc[8 * q + 5] += cn * c.y;
            acc[8 * q + 6] += cn * d.x;  acc[8 * q + 7] += cn * d.y;
        }
    }
    __syncthreads();   // halo + comb reads done -> av/f2 aliases safe

    // ---- P6: output_proj (f32 in dead LDS regions) ----
    float* av = smem;                 // [c][pix] 64x64 f32, over dead halo
    float* f2 = smem + 6272;          // [o][pix] 64x64 f32, over dead comb/fscr
    for (int j = 0; j < 16; ++j) av[(c0 + j) * 64 + lane] = acc[j];
    __syncthreads();
    float xv[64];
#pragma unroll
    for (int k = 0; k < 64; ++k) xv[k] = av[k * 64 + lane];
    float macc2 = 0.f, sacc2 = 0.f;
    for (int j = 0; j < 16; ++j) {
        const int o = c0 + j;             // uniform
        const float* wr = &w1[o * 64];
        float a0 = 0, a1 = 0, a2 = 0, a3 = 0;
#pragma unroll
        for (int k = 0; k < 64; k += 4) {
            a0 += wr[k] * xv[k];       a1 += wr[k + 1] * xv[k + 1];
            a2 += wr[k + 2] * xv[k + 2]; a3 += wr[k + 3] * xv[k + 3];
        }
        float f = (a0 + a1) + (a2 + a3) + b1[o];
        f2[o * 64 + lane] = f;
        macc2 += f; sacc2 += f * f;
    }
    pm[wv * 64 + lane] = macc2; ps[wv * 64 + lane] = sacc2;
    __syncthreads();
    float m  = (pm[lane] + pm[64 + lane] + pm[128 + lane] + pm[192 + lane]) * (1.f / 64.f);
    float va = (ps[lane] + ps[64 + lane] + ps[128 + lane] + ps[192 + lane]) * (1.f / 64.f) - m * m;
    float rstd = rsqrtf(va + EPS_LN);
    float yv[64];
#pragma unroll
    for (int k = 0; k < 64; ++k)
        yv[k] = g[k] * (f2[k * 64 + lane] - m) * rstd + be[k];
    for (int j = 0; j < 16; ++j) {
        const int o = c0 + j;             // uniform
        const float* wr = &w2[o * 64];
        float a0 = 0, a1 = 0, a2 = 0, a3 = 0;
#pragma unroll
        for (int k = 0; k < 64; k += 4) {
            a0 += wr[k] * yv[k];       a1 += wr[k + 1] * yv[k + 1];
            a2 += wr[k + 2] * yv[k + 2]; a3 += wr[k + 3] * yv[k + 3];
        }
        float z = (a0 + a1) + (a2 + a3) + b2[o];
        out[(size_t)(b * 64 + o) * HW + hw] = z;
    }
}

extern "C" void kernel_launch(void* const* d_in, const int* in_sizes, int n_in,
                              void* d_out, int out_size, void* d_ws, size_t ws_size,
                              hipStream_t stream)
{
    const float* spatial  = (const float*)d_in[0];
    const float* semantic = (const float*)d_in[1];
    const float* rp_w1 = (const float*)d_in[2];
    const float* rp_b1 = (const float*)d_in[3];
    const float* rp_g  = (const float*)d_in[4];
    const float* rp_be = (const float*)d_in[5];
    const float* rp_w2 = (const float*)d_in[6];
    const float* rp_b2 = (const float*)d_in[7];
    const float* fx_w1 = (const float*)d_in[8];
    const float* fx_b1 = (const float*)d_in[9];
    const float* fx_g  = (const float*)d_in[10];
    const float* fx_be = (const float*)d_in[11];
    const float* fx_w2 = (const float*)d_in[12];
    const float* fx_b2 = (const float*)d_in[13];
    const float* op_w1 = (const float*)d_in[14];
    const float* op_b1 = (const float*)d_in[15];
    const float* op_g  = (const float*)d_in[16];
    const float* op_be = (const float*)d_in[17];
    const float* op_w2 = (const float*)d_in[18];
    const float* op_b2 = (const float*)d_in[19];
    const float* sigma = (const float*)d_in[20];

    kfused<<<NBLK, 256, 0, stream>>>(
        semantic, spatial,
        rp_w1, rp_b1, rp_g, rp_be, rp_w2, rp_b2,
        fx_w1, fx_b1, fx_g, fx_be, fx_w2, fx_b2,
        op_w1, op_b1, op_g, op_be, op_w2, op_b2,
        sigma, (float*)d_out);
}

// Round 13
// 221.649 us; speedup vs baseline: 1.1793x; 1.1793x over previous
//
#include <hip/hip_runtime.h>

typedef unsigned short ushort;
typedef unsigned int uint;

constexpr int B = 2, C = 64, H = 112, W = 112;
constexpr int HW = H * W;          // 12544
constexpr int NPIX = B * HW;       // 25088
constexpr int NBLK = 392;          // 8 patches x 49 tiles
constexpr float EPS_LN = 1e-6f, EPS_NORM = 1e-7f;

__device__ __forceinline__ float rcp_fast(float x) { return __builtin_amdgcn_rcpf(x); }
__device__ __forceinline__ float sigmoid_f(float x) { return rcp_fast(1.f + __expf(-x)); }
// Force wave-uniformity so the compiler emits s_load for weight rows.
__device__ __forceinline__ int uni(int x) { return __builtin_amdgcn_readfirstlane(x); }

// f32 -> bf16 bits (round-nearest-even) + pair pack/unpack.
__device__ __forceinline__ ushort rne16(float x) {
    uint u = __float_as_uint(x);
    u += 0x7fffu + ((u >> 16) & 1u);
    return (ushort)(u >> 16);
}
__device__ __forceinline__ uint pack2(float a, float b) {
    return (uint)rne16(a) | ((uint)rne16(b) << 16);
}
__device__ __forceinline__ float2 up2(uint u) {
    return make_float2(__uint_as_float(u << 16), __uint_as_float(u & 0xffff0000u));
}

// XCD-patch swizzle: blk&7 -> (image, quadrant) on one XCD; blk>>3 -> tile in
// the 7x7-tile patch. Patch working set fits the 4 MB per-XCD L2.
__device__ __forceinline__ void decode_blk(int blk, int& b, int& ty, int& tx) {
    int p8 = blk & 7, i = blk >> 3;
    b = p8 >> 2;
    int quad = p8 & 3;
    int lty = i / 7, ltx = i - lty * 7;
    ty = (quad >> 1) * 7 + lty;
    tx = (quad & 1) * 7 + ltx;
}

// ---------------------------------------------------------------------------
// Producer-consumer fused kernel. Each block:
//   1) produces range_proj px (bf16) + sqnorm for its OWN 8x8 tile (r11 k1
//      structure: lane=pixel, 4 waves x 16 outputs, s_load weights),
//   2) signals a device-scope per-tile flag,
//   3) spin-waits on its <=8 neighbor tiles' flags,
//   4) runs bilateral weights + gated fixup + normalize + neighborhood
//      reduction + output_proj (r11 k23 body, bf16 LDS halos).
// Deadlock-free: 392 blocks all co-resident (54KB LDS -> 2 blocks/CU, 392<512)
// and every block signals before waiting.
// ---------------------------------------------------------------------------
__global__ __launch_bounds__(256, 2) void kfused(
    const float* __restrict__ sem,  const float* __restrict__ spat,
    const float* __restrict__ rw1, const float* __restrict__ rb1,
    const float* __restrict__ rg,  const float* __restrict__ rbe,
    const float* __restrict__ rw2, const float* __restrict__ rb2,
    const float* __restrict__ fw1, const float* __restrict__ fb1,
    const float* __restrict__ fg,  const float* __restrict__ fbe,
    const float* __restrict__ fw2, const float* __restrict__ fb2,
    const float* __restrict__ w1, const float* __restrict__ b1,
    const float* __restrict__ g,  const float* __restrict__ be,
    const float* __restrict__ w2, const float* __restrict__ b2,
    const float* __restrict__ sigma_,
    ushort* __restrict__ px16, float* __restrict__ sqnorm, int* __restrict__ flags,
    float* __restrict__ out)
{
    __shared__ __align__(16) float smem[13508];          // 54032 B arena
    ushort* halo16 = (ushort*)smem;                      // 196x64 bf16 px/spat halo
    float*  comb   = smem + 6272;                        // 49x64
    float*  fscr   = smem + 9408;                        // 49x64 (dedicated in P3)
    float*  sqn_l  = smem + 12544;                       // 196
    float*  pm     = smem + 12740;
    float*  ps     = smem + 12996;
    float*  pt     = smem + 13252;                       // ends 13508
    float*  t_scrA = smem;                               // 64x65 over halo region
    float*  f_scrA = smem + 6272;                        // 64x64 over comb/fscr

    const int tid = threadIdx.x, lane = tid & 63, wv = tid >> 6;
    int b, ty, tx; decode_blk(blockIdx.x, b, ty, tx);
    const int h = ty * 8 + (lane >> 3), w = tx * 8 + (lane & 7);
    const int hw = h * W + w;
    const int h0 = ty * 8 - 3, w0 = tx * 8 - 3;
    const int o0 = uni(wv * 16);
    const int t_lin = b * 196 + ty * 14 + tx;

    // ============ produce: range_proj for own tile (lane = pixel) ============
    float sv[64];                        // stays live -> reused as P3's svv
#pragma unroll
    for (int k = 0; k < 64; ++k) sv[k] = sem[(size_t)(b * 64 + k) * HW + hw];

    {
        float macc = 0.f, sacc = 0.f;
        for (int j = 0; j < 16; ++j) {
            const int o = o0 + j;                 // uniform -> s_load weight row
            const float* wr = &rw1[o * 64];
            float a0 = 0, a1 = 0, a2 = 0, a3 = 0;
#pragma unroll
            for (int k = 0; k < 64; k += 4) {
                a0 += wr[k] * sv[k];       a1 += wr[k + 1] * sv[k + 1];
                a2 += wr[k + 2] * sv[k + 2]; a3 += wr[k + 3] * sv[k + 3];
            }
            float f = (a0 + a1) + (a2 + a3) + rb1[o];
            f_scrA[o * 64 + lane] = f;     // bank=lane%32: 2-way, free
            macc += f; sacc += f * f;
        }
        pm[wv * 64 + lane] = macc; ps[wv * 64 + lane] = sacc;
        __syncthreads();
        float m  = (pm[lane] + pm[64 + lane] + pm[128 + lane] + pm[192 + lane]) * (1.f / 64.f);
        float va = (ps[lane] + ps[64 + lane] + ps[128 + lane] + ps[192 + lane]) * (1.f / 64.f) - m * m;
        float rstd = rsqrtf(va + EPS_LN);

        float s[64];
#pragma unroll
        for (int k = 0; k < 64; ++k) {
            float y = rg[k] * (f_scrA[k * 64 + lane] - m) * rstd + rbe[k];
            s[k] = y * sigmoid_f(y);
        }
        float sq = 0.f;
        for (int j = 0; j < 16; ++j) {
            const int o = o0 + j;                 // uniform
            const float* wr = &rw2[o * 64];
            float a0 = 0, a1 = 0, a2 = 0, a3 = 0;
#pragma unroll
            for (int k = 0; k < 64; k += 4) {
                a0 += wr[k] * s[k];        a1 += wr[k + 1] * s[k + 1];
                a2 += wr[k + 2] * s[k + 2]; a3 += wr[k + 3] * s[k + 3];
            }
            float z = (a0 + a1) + (a2 + a3) + rb2[o];
            t_scrA[o * 65 + lane] = z;     // bank=(o+lane)%32: conflict-free
            sq += z * z;
        }
        pt[wv * 64 + lane] = sq;
        __syncthreads();
        if (wv == 0)
            sqnorm[(size_t)b * HW + hw] = pt[lane] + pt[64 + lane] + pt[128 + lane] + pt[192 + lane];
        // transpose-out: wave wv stores pixels o0..o0+15; lane = channel
        for (int j = 0; j < 16; ++j) {
            int ii = o0 + j;
            int hwi = (ty * 8 + (ii >> 3)) * W + tx * 8 + (ii & 7);
            px16[((size_t)b * HW + hwi) * 64 + lane] = rne16(t_scrA[lane * 65 + ii]);
        }
    }
    __threadfence();                     // each thread's px16/sqnorm stores drain
    __syncthreads();
    if (tid == 0)
        __hip_atomic_store(&flags[t_lin], 1, __ATOMIC_RELEASE, __HIP_MEMORY_SCOPE_AGENT);

    // ============ wait for the <=8 neighbor tiles ============
    if (wv == 0) {
        bool need = false; int nb = 0;
        if (lane < 9) {
            int dyx = lane / 3 - 1, dxx = lane % 3 - 1;
            int tyn = ty + dyx, txn = tx + dxx;
            if (!(dyx == 0 && dxx == 0) &&
                (unsigned)tyn < 14u && (unsigned)txn < 14u) {
                need = true; nb = b * 196 + tyn * 14 + txn;
            }
        }
        while (__any(need)) {
            if (need &&
                __hip_atomic_load(&flags[nb], __ATOMIC_ACQUIRE, __HIP_MEMORY_SCOPE_AGENT) == 1)
                need = false;
            __builtin_amdgcn_s_sleep(1);
        }
    }
    __syncthreads();                     // neighbors' px16 visible; t_scrA dead

    // ---- P1: stage px halo (bf16): 196 rows x 8 chunks = 1568 16-B loads ----
    for (int i = 0; i < 7; ++i) {
        int idx = i * 256 + tid;
        if (idx < 1568) {
            int r = idx >> 3, q = idx & 7;
            int ry = (r * 2341) >> 15, rx = r - ry * 14;     // exact /14 for r<256
            int hh = h0 + ry, ww = w0 + rx;
            bool valid = (unsigned)hh < (unsigned)H && (unsigned)ww < (unsigned)W;
            uint4 v = make_uint4(0u, 0u, 0u, 0u);
            if (valid) v = *(const uint4*)&px16[((size_t)b * HW + hh * W + ww) * 64 + 8 * q];
            *(uint4*)&halo16[(r << 6) + ((q ^ (r & 7)) << 3)] = v;
        }
    }
    if (tid < 196) {
        int ry = (tid * 2341) >> 15, rx = tid - ry * 14;
        int hh = h0 + ry, ww = w0 + rx;
        bool valid = (unsigned)hh < (unsigned)H && (unsigned)ww < (unsigned)W;
        float v = 0.f;
        if (valid) v = sqnorm[(size_t)b * HW + hh * W + ww];
        sqn_l[tid] = v;
    }
    __syncthreads();

    // ---- P2: bilateral weights, neighbors split across waves ----
    const int rbase = (lane >> 3) * 14 + (lane & 7);
    const int rp = rbase + 45;
    float cv[64];
#pragma unroll
    for (int q = 0; q < 8; ++q) {
        uint4 v = *(const uint4*)&halo16[(rp << 6) + ((q ^ (rp & 7)) << 3)];
        float2 p0_ = up2(v.x), p1_ = up2(v.y), p2_ = up2(v.z), p3_ = up2(v.w);
        cv[8 * q + 0] = p0_.x; cv[8 * q + 1] = p0_.y;
        cv[8 * q + 2] = p1_.x; cv[8 * q + 3] = p1_.y;
        cv[8 * q + 4] = p2_.x; cv[8 * q + 5] = p2_.y;
        cv[8 * q + 6] = p3_.x; cv[8 * q + 7] = p3_.y;
    }
    const float sqc = sqn_l[rp];
    const float sg_ = sigma_[0];
    const float inv2s2 = rcp_fast(2.f * sg_ * sg_);
    for (int i = 0; i < 13; ++i) {
        int n = uni(wv + 4 * i);
        if (n < 49) {
            int ryn = n / 7, rxn = n - ryn * 7;
            int dy = ryn - 3, dx = rxn - 3;
            int rn = rbase + ryn * 14 + rxn;
            float d0 = 0, d1 = 0, d2 = 0, d3 = 0;
#pragma unroll
            for (int q = 0; q < 8; ++q) {
                uint4 v = *(const uint4*)&halo16[(rn << 6) + ((q ^ (rn & 7)) << 3)];
                float2 a = up2(v.x), bb = up2(v.y), c = up2(v.z), d = up2(v.w);
                d0 += a.x  * cv[8 * q + 0]; d1 += a.y  * cv[8 * q + 1];
                d2 += bb.x * cv[8 * q + 2]; d3 += bb.y * cv[8 * q + 3];
                d0 += c.x  * cv[8 * q + 4]; d1 += c.y  * cv[8 * q + 5];
                d2 += d.x  * cv[8 * q + 6]; d3 += d.y  * cv[8 * q + 7];
            }
            float dot = (d0 + d1) + (d2 + d3);
            float dist2 = fmaxf(sqn_l[rn] + sqc - 2.f * dot, 0.f);
            bool validn = (unsigned)(h + dy) < (unsigned)H && (unsigned)(w + dx) < (unsigned)W;
            float d2n = (float)(dy * dy + dx * dx);
            comb[n * 64 + lane] = validn ? __expf(-(dist2 * (1.f / 128.f) + d2n * inv2s2)) : 0.f;
        }
    }
    __syncthreads();   // all px-halo reads + comb writes done

    // ---- P4 (issued first, overlaps P3): restage halo with spat (bf16) ----
    {
        const int ry16 = tid >> 4, rx16 = tid & 15;
        if ((ry16 < 14) & (rx16 < 14)) {
            const int r = ry16 * 14 + rx16;
            const int hh = h0 + ry16, ww = w0 + rx16;
            const bool valid = (unsigned)hh < (unsigned)H && (unsigned)ww < (unsigned)W;
            const int soff = hh * W + ww;
            const int rsw = (r & 7), rb_ = r << 6;
#pragma unroll
            for (int cq = 0; cq < 8; ++cq) {
                uint4 v = make_uint4(0u, 0u, 0u, 0u);
                if (valid) {
                    const float* sp = &spat[(size_t)(b * 64 + 8 * cq) * HW + soff];
                    v.x = pack2(sp[0],      sp[HW]);
                    v.y = pack2(sp[2 * HW], sp[3 * HW]);
                    v.z = pack2(sp[4 * HW], sp[5 * HW]);
                    v.w = pack2(sp[6 * HW], sp[7 * HW]);
                }
                *(uint4*)&halo16[rb_ + ((cq ^ rsw) << 3)] = v;
            }
        }
    }

    // ---- P3: gated fixup (fscr dedicated; sv reused as semantic vector) ----
    float cb[49];
#pragma unroll
    for (int n = 0; n < 49; ++n) cb[n] = comb[n * 64 + lane];
    float macc = 0.f, sacc = 0.f;
    for (int i = 0; i < 13; ++i) {
        const int o = uni(wv + 4 * i);   // uniform -> s_load weight row
        if (o < 49) {
            const float* wr = &fw1[o * 113];
            float a0 = 0, a1 = 0, a2 = 0, a3 = 0;
#pragma unroll
            for (int k = 0; k < 48; k += 4) {
                a0 += wr[k] * cb[k];       a1 += wr[k + 1] * cb[k + 1];
                a2 += wr[k + 2] * cb[k + 2]; a3 += wr[k + 3] * cb[k + 3];
            }
            a0 += wr[48] * cb[48];
            const float* wr2 = wr + 49;
#pragma unroll
            for (int k = 0; k < 64; k += 4) {
                a0 += wr2[k] * sv[k];       a1 += wr2[k + 1] * sv[k + 1];
                a2 += wr2[k + 2] * sv[k + 2]; a3 += wr2[k + 3] * sv[k + 3];
            }
            float f = (a0 + a1) + (a2 + a3) + fb1[o];
            fscr[o * 64 + lane] = f;
            macc += f; sacc += f * f;
        }
    }
    pm[wv * 64 + lane] = macc; ps[wv * 64 + lane] = sacc;
    __syncthreads();
    {
        float m  = (pm[lane] + pm[64 + lane] + pm[128 + lane] + pm[192 + lane]) * (1.f / 49.f);
        float va = (ps[lane] + ps[64 + lane] + ps[128 + lane] + ps[192 + lane]) * (1.f / 49.f) - m * m;
        float rstd = rsqrtf(va + EPS_LN);
        float s[49];
#pragma unroll
        for (int k = 0; k < 49; ++k) {
            float y = fg[k] * (fscr[k * 64 + lane] - m) * rstd + fbe[k];
            s[k] = y * sigmoid_f(y);
        }
        float tacc = 0.f;
        for (int i = 0; i < 13; ++i) {
            const int o = uni(wv + 4 * i);
            if (o < 49) {
                const float* wr = &fw2[o * 49];
                float a0 = 0, a1 = 0, a2 = 0, a3 = 0;
#pragma unroll
                for (int k = 0; k < 48; k += 4) {
                    a0 += wr[k] * s[k];       a1 += wr[k + 1] * s[k + 1];
                    a2 += wr[k + 2] * s[k + 2]; a3 += wr[k + 3] * s[k + 3];
                }
                a0 += wr[48] * s[48];
                float fo = (a0 + a1) + (a2 + a3) + fb2[o];
                float gate = 1.f + sigmoid_f(fo);
                float cx = comb[o * 64 + lane] * gate;   // own rows: no race
                comb[o * 64 + lane] = cx;
                tacc += cx;
            }
        }
        pt[wv * 64 + lane] = tacc;
    }
    __syncthreads();   // P3 done AND P4 staging visible
    const float inv = rcp_fast(pt[lane] + pt[64 + lane] + pt[128 + lane] + pt[192 + lane] + EPS_NORM);

    // ---- P5: weighted neighborhood reduction (bf16 spat halo) ----
    const int c0 = uni(wv * 16);
    const int qq0 = c0 >> 3;            // wave's two 8-ch chunks
    float acc[16];
#pragma unroll
    for (int j = 0; j < 16; ++j) acc[j] = 0.f;
    for (int n = 0; n < 49; ++n) {
        int ryn = n / 7, rxn = n - ryn * 7;
        int rn = rbase + ryn * 14 + rxn;
        float cn = comb[n * 64 + lane] * inv;
        const int rb_ = rn << 6, rsw = rn & 7;
#pragma unroll
        for (int q = 0; q < 2; ++q) {
            uint4 v = *(const uint4*)&halo16[rb_ + (((qq0 + q) ^ rsw) << 3)];
            float2 a = up2(v.x), bb = up2(v.y), c = up2(v.z), d = up2(v.w);
            acc[8 * q + 0] += cn * a.x;  acc[8 * q + 1] += cn * a.y;
            acc[8 * q + 2] += cn * bb.x; acc[8 * q + 3] += cn * bb.y;
            acc[8 * q + 4] += cn * c.x;  acc[8 * q + 5] += cn * c.y;
            acc[8 * q + 6] += cn * d.x;  acc[8 * q + 7] += cn * d.y;
        }
    }
    __syncthreads();   // halo + comb reads done -> av/f2 aliases safe

    // ---- P6: output_proj (f32 in dead LDS regions) ----
    float* av = smem;                 // [c][pix] 64x64 f32, over dead halo
    float* f2 = smem + 6272;          // [o][pix] 64x64 f32, over dead comb/fscr
    for (int j = 0; j < 16; ++j) av[(c0 + j) * 64 + lane] = acc[j];
    __syncthreads();
    float xv[64];
#pragma unroll
    for (int k = 0; k < 64; ++k) xv[k] = av[k * 64 + lane];
    float macc2 = 0.f, sacc2 = 0.f;
    for (int j = 0; j < 16; ++j) {
        const int o = c0 + j;             // uniform
        const float* wr = &w1[o * 64];
        float a0 = 0, a1 = 0, a2 = 0, a3 = 0;
#pragma unroll
        for (int k = 0; k < 64; k += 4) {
            a0 += wr[k] * xv[k];       a1 += wr[k + 1] * xv[k + 1];
            a2 += wr[k + 2] * xv[k + 2]; a3 += wr[k + 3] * xv[k + 3];
        }
        float f = (a0 + a1) + (a2 + a3) + b1[o];
        f2[o * 64 + lane] = f;
        macc2 += f; sacc2 += f * f;
    }
    pm[wv * 64 + lane] = macc2; ps[wv * 64 + lane] = sacc2;
    __syncthreads();
    float m  = (pm[lane] + pm[64 + lane] + pm[128 + lane] + pm[192 + lane]) * (1.f / 64.f);
    float va = (ps[lane] + ps[64 + lane] + ps[128 + lane] + ps[192 + lane]) * (1.f / 64.f) - m * m;
    float rstd = rsqrtf(va + EPS_LN);
    float yv[64];
#pragma unroll
    for (int k = 0; k < 64; ++k)
        yv[k] = g[k] * (f2[k * 64 + lane] - m) * rstd + be[k];
    for (int j = 0; j < 16; ++j) {
        const int o = c0 + j;             // uniform
        const float* wr = &w2[o * 64];
        float a0 = 0, a1 = 0, a2 = 0, a3 = 0;
#pragma unroll
        for (int k = 0; k < 64; k += 4) {
            a0 += wr[k] * yv[k];       a1 += wr[k + 1] * yv[k + 1];
            a2 += wr[k + 2] * yv[k + 2]; a3 += wr[k + 3] * yv[k + 3];
        }
        float z = (a0 + a1) + (a2 + a3) + b2[o];
        out[(size_t)(b * 64 + o) * HW + hw] = z;
    }
}

extern "C" void kernel_launch(void* const* d_in, const int* in_sizes, int n_in,
                              void* d_out, int out_size, void* d_ws, size_t ws_size,
                              hipStream_t stream)
{
    const float* spatial  = (const float*)d_in[0];
    const float* semantic = (const float*)d_in[1];
    const float* rp_w1 = (const float*)d_in[2];
    const float* rp_b1 = (const float*)d_in[3];
    const float* rp_g  = (const float*)d_in[4];
    const float* rp_be = (const float*)d_in[5];
    const float* rp_w2 = (const float*)d_in[6];
    const float* rp_b2 = (const float*)d_in[7];
    const float* fx_w1 = (const float*)d_in[8];
    const float* fx_b1 = (const float*)d_in[9];
    const float* fx_g  = (const float*)d_in[10];
    const float* fx_be = (const float*)d_in[11];
    const float* fx_w2 = (const float*)d_in[12];
    const float* fx_b2 = (const float*)d_in[13];
    const float* op_w1 = (const float*)d_in[14];
    const float* op_b1 = (const float*)d_in[15];
    const float* op_g  = (const float*)d_in[16];
    const float* op_be = (const float*)d_in[17];
    const float* op_w2 = (const float*)d_in[18];
    const float* op_b2 = (const float*)d_in[19];
    const float* sigma = (const float*)d_in[20];

    // workspace: px16 (bf16) | sqnorm (f32) | flags (int, poisoned 0xAA != 1)
    ushort* px16  = (ushort*)d_ws;
    float* sqnorm = (float*)((char*)d_ws + (size_t)NPIX * 64 * 2);
    int*   flags  = (int*)((char*)d_ws + (size_t)NPIX * 64 * 2 + (size_t)NPIX * 4);

    kfused<<<NBLK, 256, 0, stream>>>(
        semantic, spatial,
        rp_w1, rp_b1, rp_g, rp_be, rp_w2, rp_b2,
        fx_w1, fx_b1, fx_g, fx_be, fx_w2, fx_b2,
        op_w1, op_b1, op_g, op_be, op_w2, op_b2,
        sigma, px16, sqnorm, flags, (float*)d_out);
}

// Round 14
// 183.280 us; speedup vs baseline: 1.4262x; 1.2093x over previous
//
#include <hip/hip_runtime.h>

typedef unsigned short ushort;
typedef unsigned int uint;

constexpr int B = 2, C = 64, H = 112, W = 112;
constexpr int HW = H * W;          // 12544
constexpr int NPIX = B * HW;       // 25088
constexpr int NBLK = 392;          // 8 patches x 49 tiles
constexpr float EPS_LN = 1e-6f, EPS_NORM = 1e-7f;

__device__ __forceinline__ float rcp_fast(float x) { return __builtin_amdgcn_rcpf(x); }
__device__ __forceinline__ float sigmoid_f(float x) { return rcp_fast(1.f + __expf(-x)); }
// Force wave-uniformity so the compiler emits s_load for weight rows.
__device__ __forceinline__ int uni(int x) { return __builtin_amdgcn_readfirstlane(x); }

// f32 -> bf16 bits (round-nearest-even) + pair pack/unpack.
__device__ __forceinline__ ushort rne16(float x) {
    uint u = __float_as_uint(x);
    u += 0x7fffu + ((u >> 16) & 1u);
    return (ushort)(u >> 16);
}
__device__ __forceinline__ uint pack2(float a, float b) {
    return (uint)rne16(a) | ((uint)rne16(b) << 16);
}
__device__ __forceinline__ float2 up2(uint u) {
    return make_float2(__uint_as_float(u << 16), __uint_as_float(u & 0xffff0000u));
}

// XCD-patch swizzle (BOTH kernels -> producer/consumer share an XCD L2):
// blk&7 -> (image, quadrant); blk>>3 -> tile in the 7x7-tile patch.
__device__ __forceinline__ void decode_blk(int blk, int& b, int& ty, int& tx) {
    int p8 = blk & 7, i = blk >> 3;
    b = p8 >> 2;
    int quad = p8 & 3;
    int lty = i / 7, ltx = i - lty * 7;
    ty = (quad >> 1) * 7 + lty;
    tx = (quad & 1) * 7 + ltx;
}

// ---------------------------------------------------------------------------
// k1: px = range_proj(semantic) -> px16[p][64] (bf16) + sqnorm[p].
// 8x8 tile per block with the SAME XCD swizzle as k23, so k23's halo reads
// hit the producing XCD's L2. lane=pixel, 4 waves x 16 outputs, s_load weights.
// px16 stores stay 128-B coalesced via LDS transpose.
// ---------------------------------------------------------------------------
__global__ __launch_bounds__(256) void k1_range_proj(
    const float* __restrict__ sem,
    const float* __restrict__ w1, const float* __restrict__ b1,
    const float* __restrict__ g,  const float* __restrict__ be,
    const float* __restrict__ w2, const float* __restrict__ b2,
    ushort* __restrict__ px16, float* __restrict__ sqnorm)
{
    __shared__ float f_scr[64 * 64];    // [o][pix]
    __shared__ float t_scr[64 * 65];    // [o][pix] pitch 65 (transpose buffer)
    __shared__ float pm[4 * 64], ps[4 * 64], p2[4 * 64];

    const int tid = threadIdx.x, lane = tid & 63, wv = tid >> 6;
    int b, ty, tx; decode_blk(blockIdx.x, b, ty, tx);
    const int h = ty * 8 + (lane >> 3), w = tx * 8 + (lane & 7);
    const int hw = h * W + w;

    float sv[64];
#pragma unroll
    for (int k = 0; k < 64; ++k) sv[k] = sem[(size_t)(b * 64 + k) * HW + hw];

    const int o0 = uni(wv * 16);
    float macc = 0.f, sacc = 0.f;
    for (int j = 0; j < 16; ++j) {
        const int o = o0 + j;                 // uniform -> s_load weight row
        const float* wr = &w1[o * 64];
        float a0 = 0, a1 = 0, a2 = 0, a3 = 0;
#pragma unroll
        for (int k = 0; k < 64; k += 4) {
            a0 += wr[k] * sv[k];       a1 += wr[k + 1] * sv[k + 1];
            a2 += wr[k + 2] * sv[k + 2]; a3 += wr[k + 3] * sv[k + 3];
        }
        float f = (a0 + a1) + (a2 + a3) + b1[o];
        f_scr[o * 64 + lane] = f;      // bank=lane%32: 2-way, free
        macc += f; sacc += f * f;
    }
    pm[wv * 64 + lane] = macc; ps[wv * 64 + lane] = sacc;
    __syncthreads();
    float m  = (pm[lane] + pm[64 + lane] + pm[128 + lane] + pm[192 + lane]) * (1.f / 64.f);
    float va = (ps[lane] + ps[64 + lane] + ps[128 + lane] + ps[192 + lane]) * (1.f / 64.f) - m * m;
    float rstd = rsqrtf(va + EPS_LN);

    float s[64];
#pragma unroll
    for (int k = 0; k < 64; ++k) {
        float y = g[k] * (f_scr[k * 64 + lane] - m) * rstd + be[k];
        s[k] = y * sigmoid_f(y);
    }
    float sq = 0.f;
    for (int j = 0; j < 16; ++j) {
        const int o = o0 + j;                 // uniform
        const float* wr = &w2[o * 64];
        float a0 = 0, a1 = 0, a2 = 0, a3 = 0;
#pragma unroll
        for (int k = 0; k < 64; k += 4) {
            a0 += wr[k] * s[k];        a1 += wr[k + 1] * s[k + 1];
            a2 += wr[k + 2] * s[k + 2]; a3 += wr[k + 3] * s[k + 3];
        }
        float z = (a0 + a1) + (a2 + a3) + b2[o];
        t_scr[o * 65 + lane] = z;      // bank=(o+lane)%32: conflict-free
        sq += z * z;                   // sqnorm from f32 z
    }
    p2[wv * 64 + lane] = sq;
    __syncthreads();
    if (wv == 0)
        sqnorm[(size_t)b * HW + hw] = p2[lane] + p2[64 + lane] + p2[128 + lane] + p2[192 + lane];
    // transpose-out: wave wv stores pixels o0..o0+15 (128-B bf16 rows)
    for (int j = 0; j < 16; ++j) {
        int ii = o0 + j;
        int hwi = (ty * 8 + (ii >> 3)) * W + tx * 8 + (ii & 7);
        px16[((size_t)b * HW + hwi) * 64 + lane] = rne16(t_scr[lane * 65 + ii]);
    }
}

// ---------------------------------------------------------------------------
// k23: bilateral weights + gated fixup + normalize + neighborhood reduction +
// output_proj. 256 threads / 8x8 tile. Weights via s_load (uniform o).
// BOTH halos (px + spat, bf16) resident: spat staging issues at kernel entry
// and overlaps the px staging + svv prefetch. bf16 halo row r = 128 B =
// 8 chunks of 16 B; chunk q stored at q^(r&7) -> b128 at the LDS floor.
// ---------------------------------------------------------------------------
__global__ __launch_bounds__(256, 2) void k23_fused(
    const ushort* __restrict__ px16, const float* __restrict__ sqnorm,
    const float* __restrict__ sem,  const float* __restrict__ spat,
    const float* __restrict__ fw1, const float* __restrict__ fb1,
    const float* __restrict__ fg,  const float* __restrict__ fbe,
    const float* __restrict__ fw2, const float* __restrict__ fb2,
    const float* __restrict__ w1, const float* __restrict__ b1,
    const float* __restrict__ g,  const float* __restrict__ be,
    const float* __restrict__ w2, const float* __restrict__ b2,
    const float* __restrict__ sigma_, float* __restrict__ out)
{
    __shared__ __align__(16) float smem[19780];          // 79120 B arena
    ushort* haloA = (ushort*)smem;                       // px halo (bf16)
    ushort* haloB = (ushort*)(smem + 6272);              // spat halo (bf16)
    float*  comb  = smem + 12544;                        // 49x64
    float*  fscr  = smem + 15680;                        // 49x64 (dedicated)
    float*  sqn_l = smem + 18816;                        // 196
    float*  pm    = smem + 19012;
    float*  ps    = smem + 19268;
    float*  pt    = smem + 19524;                        // ends 19780

    const int tid = threadIdx.x, lane = tid & 63, wv = tid >> 6;
    int b, ty, tx; decode_blk(blockIdx.x, b, ty, tx);
    const int h = ty * 8 + (lane >> 3), w = tx * 8 + (lane & 7);
    const int hw = h * W + w;
    const int h0 = ty * 8 - 3, w0 = tx * 8 - 3;

    // ---- svv prefetch (P3 input): overlaps both stagings ----
    float sv[64];
#pragma unroll
    for (int k = 0; k < 64; ++k) sv[k] = sem[(size_t)(b * 64 + k) * HW + hw];

    // ---- P4 (hoisted): stage spat halo -> haloB (bf16) ----
    {
        const int ry16 = tid >> 4, rx16 = tid & 15;
        if ((ry16 < 14) & (rx16 < 14)) {
            const int r = ry16 * 14 + rx16;
            const int hh = h0 + ry16, ww = w0 + rx16;
            const bool valid = (unsigned)hh < (unsigned)H && (unsigned)ww < (unsigned)W;
            const int soff = hh * W + ww;
            const int rsw = (r & 7), rb_ = r << 6;
#pragma unroll
            for (int cq = 0; cq < 8; ++cq) {
                uint4 v = make_uint4(0u, 0u, 0u, 0u);
                if (valid) {
                    const float* sp = &spat[(size_t)(b * 64 + 8 * cq) * HW + soff];
                    v.x = pack2(sp[0],      sp[HW]);
                    v.y = pack2(sp[2 * HW], sp[3 * HW]);
                    v.z = pack2(sp[4 * HW], sp[5 * HW]);
                    v.w = pack2(sp[6 * HW], sp[7 * HW]);
                }
                *(uint4*)&haloB[rb_ + ((cq ^ rsw) << 3)] = v;
            }
        }
    }

    // ---- P1: stage px halo -> haloA (bf16): 1568 16-B loads ----
    for (int i = 0; i < 7; ++i) {
        int idx = i * 256 + tid;
        if (idx < 1568) {
            int r = idx >> 3, q = idx & 7;
            int ry = (r * 2341) >> 15, rx = r - ry * 14;     // exact /14 for r<256
            int hh = h0 + ry, ww = w0 + rx;
            bool valid = (unsigned)hh < (unsigned)H && (unsigned)ww < (unsigned)W;
            uint4 v = make_uint4(0u, 0u, 0u, 0u);
            if (valid) v = *(const uint4*)&px16[((size_t)b * HW + hh * W + ww) * 64 + 8 * q];
            *(uint4*)&haloA[(r << 6) + ((q ^ (r & 7)) << 3)] = v;
        }
    }
    if (tid < 196) {
        int ry = (tid * 2341) >> 15, rx = tid - ry * 14;
        int hh = h0 + ry, ww = w0 + rx;
        bool valid = (unsigned)hh < (unsigned)H && (unsigned)ww < (unsigned)W;
        float v = 0.f;
        if (valid) v = sqnorm[(size_t)b * HW + hh * W + ww];
        sqn_l[tid] = v;
    }
    __syncthreads();

    // ---- P2: bilateral weights, neighbors split across waves ----
    const int rbase = (lane >> 3) * 14 + (lane & 7);
    const int rp = rbase + 45;
    float cv[64];
#pragma unroll
    for (int q = 0; q < 8; ++q) {
        uint4 v = *(const uint4*)&haloA[(rp << 6) + ((q ^ (rp & 7)) << 3)];
        float2 p0_ = up2(v.x), p1_ = up2(v.y), p2_ = up2(v.z), p3_ = up2(v.w);
        cv[8 * q + 0] = p0_.x; cv[8 * q + 1] = p0_.y;
        cv[8 * q + 2] = p1_.x; cv[8 * q + 3] = p1_.y;
        cv[8 * q + 4] = p2_.x; cv[8 * q + 5] = p2_.y;
        cv[8 * q + 6] = p3_.x; cv[8 * q + 7] = p3_.y;
    }
    const float sqc = sqn_l[rp];
    const float sg_ = sigma_[0];
    const float inv2s2 = rcp_fast(2.f * sg_ * sg_);
    for (int i = 0; i < 13; ++i) {
        int n = uni(wv + 4 * i);
        if (n < 49) {
            int ryn = n / 7, rxn = n - ryn * 7;
            int dy = ryn - 3, dx = rxn - 3;
            int rn = rbase + ryn * 14 + rxn;
            float d0 = 0, d1 = 0, d2 = 0, d3 = 0;
#pragma unroll
            for (int q = 0; q < 8; ++q) {
                uint4 v = *(const uint4*)&haloA[(rn << 6) + ((q ^ (rn & 7)) << 3)];
                float2 a = up2(v.x), bb = up2(v.y), c = up2(v.z), d = up2(v.w);
                d0 += a.x  * cv[8 * q + 0]; d1 += a.y  * cv[8 * q + 1];
                d2 += bb.x * cv[8 * q + 2]; d3 += bb.y * cv[8 * q + 3];
                d0 += c.x  * cv[8 * q + 4]; d1 += c.y  * cv[8 * q + 5];
                d2 += d.x  * cv[8 * q + 6]; d3 += d.y  * cv[8 * q + 7];
            }
            float dot = (d0 + d1) + (d2 + d3);
            float dist2 = fmaxf(sqn_l[rn] + sqc - 2.f * dot, 0.f);
            bool validn = (unsigned)(h + dy) < (unsigned)H && (unsigned)(w + dx) < (unsigned)W;
            float d2n = (float)(dy * dy + dx * dx);
            comb[n * 64 + lane] = validn ? __expf(-(dist2 * (1.f / 128.f) + d2n * inv2s2)) : 0.f;
        }
    }
    __syncthreads();   // px-halo reads + comb writes done

    // ---- P3: gated fixup (fscr dedicated; sv reused as semantic vector) ----
    float cb[49];
#pragma unroll
    for (int n = 0; n < 49; ++n) cb[n] = comb[n * 64 + lane];
    float macc = 0.f, sacc = 0.f;
    for (int i = 0; i < 13; ++i) {
        const int o = uni(wv + 4 * i);   // uniform -> s_load weight row
        if (o < 49) {
            const float* wr = &fw1[o * 113];
            float a0 = 0, a1 = 0, a2 = 0, a3 = 0;
#pragma unroll
            for (int k = 0; k < 48; k += 4) {
                a0 += wr[k] * cb[k];       a1 += wr[k + 1] * cb[k + 1];
                a2 += wr[k + 2] * cb[k + 2]; a3 += wr[k + 3] * cb[k + 3];
            }
            a0 += wr[48] * cb[48];
            const float* wr2 = wr + 49;
#pragma unroll
            for (int k = 0; k < 64; k += 4) {
                a0 += wr2[k] * sv[k];       a1 += wr2[k + 1] * sv[k + 1];
                a2 += wr2[k + 2] * sv[k + 2]; a3 += wr2[k + 3] * sv[k + 3];
            }
            float f = (a0 + a1) + (a2 + a3) + fb1[o];
            fscr[o * 64 + lane] = f;
            macc += f; sacc += f * f;
        }
    }
    pm[wv * 64 + lane] = macc; ps[wv * 64 + lane] = sacc;
    __syncthreads();
    {
        float m  = (pm[lane] + pm[64 + lane] + pm[128 + lane] + pm[192 + lane]) * (1.f / 49.f);
        float va = (ps[lane] + ps[64 + lane] + ps[128 + lane] + ps[192 + lane]) * (1.f / 49.f) - m * m;
        float rstd = rsqrtf(va + EPS_LN);
        float s[49];
#pragma unroll
        for (int k = 0; k < 49; ++k) {
            float y = fg[k] * (fscr[k * 64 + lane] - m) * rstd + fbe[k];
            s[k] = y * sigmoid_f(y);
        }
        float tacc = 0.f;
        for (int i = 0; i < 13; ++i) {
            const int o = uni(wv + 4 * i);
            if (o < 49) {
                const float* wr = &fw2[o * 49];
                float a0 = 0, a1 = 0, a2 = 0, a3 = 0;
#pragma unroll
                for (int k = 0; k < 48; k += 4) {
                    a0 += wr[k] * s[k];       a1 += wr[k + 1] * s[k + 1];
                    a2 += wr[k + 2] * s[k + 2]; a3 += wr[k + 3] * s[k + 3];
                }
                a0 += wr[48] * s[48];
                float fo = (a0 + a1) + (a2 + a3) + fb2[o];
                float gate = 1.f + sigmoid_f(fo);
                float cx = comb[o * 64 + lane] * gate;   // own rows: no race
                comb[o * 64 + lane] = cx;
                tacc += cx;
            }
        }
        pt[wv * 64 + lane] = tacc;
    }
    __syncthreads();
    const float inv = rcp_fast(pt[lane] + pt[64 + lane] + pt[128 + lane] + pt[192 + lane] + EPS_NORM);

    // ---- P5: weighted neighborhood reduction (haloB, staged at entry) ----
    const int c0 = uni(wv * 16);
    const int qq0 = c0 >> 3;            // wave's two 8-ch chunks
    float acc[16];
#pragma unroll
    for (int j = 0; j < 16; ++j) acc[j] = 0.f;
    for (int n = 0; n < 49; ++n) {
        int ryn = n / 7, rxn = n - ryn * 7;
        int rn = rbase + ryn * 14 + rxn;
        float cn = comb[n * 64 + lane] * inv;
        const int rb_ = rn << 6, rsw = rn & 7;
#pragma unroll
        for (int q = 0; q < 2; ++q) {
            uint4 v = *(const uint4*)&haloB[rb_ + (((qq0 + q) ^ rsw) << 3)];
            float2 a = up2(v.x), bb = up2(v.y), c = up2(v.z), d = up2(v.w);
            acc[8 * q + 0] += cn * a.x;  acc[8 * q + 1] += cn * a.y;
            acc[8 * q + 2] += cn * bb.x; acc[8 * q + 3] += cn * bb.y;
            acc[8 * q + 4] += cn * c.x;  acc[8 * q + 5] += cn * c.y;
            acc[8 * q + 6] += cn * d.x;  acc[8 * q + 7] += cn * d.y;
        }
    }
    __syncthreads();   // haloA/haloB/comb reads done -> av/f2 overlays safe

    // ---- P6: output_proj (f32 overlays on the two dead halo regions) ----
    float* av = smem;                 // 64x64 f32 over dead haloA
    float* f2 = smem + 6272;          // 64x64 f32 over dead haloB
    for (int j = 0; j < 16; ++j) av[(c0 + j) * 64 + lane] = acc[j];
    __syncthreads();
    float xv[64];
#pragma unroll
    for (int k = 0; k < 64; ++k) xv[k] = av[k * 64 + lane];
    float macc2 = 0.f, sacc2 = 0.f;
    for (int j = 0; j < 16; ++j) {
        const int o = c0 + j;             // uniform
        const float* wr = &w1[o * 64];
        float a0 = 0, a1 = 0, a2 = 0, a3 = 0;
#pragma unroll
        for (int k = 0; k < 64; k += 4) {
            a0 += wr[k] * xv[k];       a1 += wr[k + 1] * xv[k + 1];
            a2 += wr[k + 2] * xv[k + 2]; a3 += wr[k + 3] * xv[k + 3];
        }
        float f = (a0 + a1) + (a2 + a3) + b1[o];
        f2[o * 64 + lane] = f;
        macc2 += f; sacc2 += f * f;
    }
    pm[wv * 64 + lane] = macc2; ps[wv * 64 + lane] = sacc2;
    __syncthreads();
    float m  = (pm[lane] + pm[64 + lane] + pm[128 + lane] + pm[192 + lane]) * (1.f / 64.f);
    float va = (ps[lane] + ps[64 + lane] + ps[128 + lane] + ps[192 + lane]) * (1.f / 64.f) - m * m;
    float rstd = rsqrtf(va + EPS_LN);
    float yv[64];
#pragma unroll
    for (int k = 0; k < 64; ++k)
        yv[k] = g[k] * (f2[k * 64 + lane] - m) * rstd + be[k];
    for (int j = 0; j < 16; ++j) {
        const int o = c0 + j;             // uniform
        const float* wr = &w2[o * 64];
        float a0 = 0, a1 = 0, a2 = 0, a3 = 0;
#pragma unroll
        for (int k = 0; k < 64; k += 4) {
            a0 += wr[k] * yv[k];       a1 += wr[k + 1] * yv[k + 1];
            a2 += wr[k + 2] * yv[k + 2]; a3 += wr[k + 3] * yv[k + 3];
        }
        float z = (a0 + a1) + (a2 + a3) + b2[o];
        out[(size_t)(b * 64 + o) * HW + hw] = z;
    }
}

extern "C" void kernel_launch(void* const* d_in, const int* in_sizes, int n_in,
                              void* d_out, int out_size, void* d_ws, size_t ws_size,
                              hipStream_t stream)
{
    const float* spatial  = (const float*)d_in[0];
    const float* semantic = (const float*)d_in[1];
    const float* rp_w1 = (const float*)d_in[2];
    const float* rp_b1 = (const float*)d_in[3];
    const float* rp_g  = (const float*)d_in[4];
    const float* rp_be = (const float*)d_in[5];
    const float* rp_w2 = (const float*)d_in[6];
    const float* rp_b2 = (const float*)d_in[7];
    const float* fx_w1 = (const float*)d_in[8];
    const float* fx_b1 = (const float*)d_in[9];
    const float* fx_g  = (const float*)d_in[10];
    const float* fx_be = (const float*)d_in[11];
    const float* fx_w2 = (const float*)d_in[12];
    const float* fx_b2 = (const float*)d_in[13];
    const float* op_w1 = (const float*)d_in[14];
    const float* op_b1 = (const float*)d_in[15];
    const float* op_g  = (const float*)d_in[16];
    const float* op_be = (const float*)d_in[17];
    const float* op_w2 = (const float*)d_in[18];
    const float* op_b2 = (const float*)d_in[19];
    const float* sigma = (const float*)d_in[20];

    ushort* px16  = (ushort*)d_ws;                              // 3.21 MB
    float* sqnorm = (float*)((char*)d_ws + (size_t)NPIX * 64 * 2);

    k1_range_proj<<<NBLK, 256, 0, stream>>>(
        semantic, rp_w1, rp_b1, rp_g, rp_be, rp_w2, rp_b2, px16, sqnorm);
    k23_fused<<<NBLK, 256, 0, stream>>>(
        px16, sqnorm, semantic, spatial,
        fx_w1, fx_b1, fx_g, fx_be, fx_w2, fx_b2,
        op_w1, op_b1, op_g, op_be, op_w2, op_b2,
        sigma, (float*)d_out);
}